// Round 1
// baseline (579.313 us; speedup 1.0000x reference)
//
#include <hip/hip_runtime.h>
#include <hip/hip_bf16.h>
#include <cstdint>
#include <cstddef>

#define B_   32
#define S_   2048
#define DH_  1024
#define DF_  1024
#define DM_  512
#define MTOT (B_ * S_)   // 65536

typedef __attribute__((ext_vector_type(8))) short bf16x8;
typedef __attribute__((ext_vector_type(4))) float f32x4;

#define AS1 __attribute__((address_space(1)))
#define AS3 __attribute__((address_space(3)))

static __device__ __forceinline__ void load_lds16(const void* g, void* l) {
    __builtin_amdgcn_global_load_lds((const AS1 unsigned*)g, (AS3 unsigned*)l,
                                     16, 0, 0);
}

// fp32 pair -> packed bf16, round-half-up (cheap)
static __device__ __forceinline__ unsigned pack_rhu(float a, float b) {
    unsigned ua = (__float_as_uint(a) + 0x8000u) >> 16;
    unsigned ub = (__float_as_uint(b) + 0x8000u) & 0xFFFF0000u;
    return ua | ub;
}

static __device__ __forceinline__ float tanh_fast(float x) {
    float e = __expf(2.0f * x);
    return 1.0f - 2.0f / (e + 1.0f);
}

static __device__ __forceinline__ float bflo(unsigned v) {
    return __uint_as_float(v << 16);
}
static __device__ __forceinline__ float bfhi(unsigned v) {
    return __uint_as_float(v & 0xFFFF0000u);
}

// ---------------------------------------------------------------------------
// embh[b][m] = dot(hidden[b], W1h[m]) + b1h[m] + b1f[m]
// ---------------------------------------------------------------------------
__global__ __launch_bounds__(256) void k_embh(
    const float* __restrict__ hidden, const float* __restrict__ W1h,
    const float* __restrict__ b1h, const float* __restrict__ b1f,
    float* __restrict__ embh)
{
    int b  = blockIdx.x;
    int mg = blockIdx.y;
    int t  = threadIdx.x;
    int m  = mg * 64 + (t >> 2);
    int kp = (t & 3) * 256;
    const float4* h4 = (const float4*)(hidden + (size_t)b * DH_ + kp);
    const float4* w4 = (const float4*)(W1h + (size_t)m * DH_ + kp);
    float s = 0.0f;
    #pragma unroll 8
    for (int i = 0; i < 64; ++i) {
        float4 a = h4[i];
        float4 w = w4[i];
        s += a.x * w.x + a.y * w.y + a.z * w.z + a.w * w.w;
    }
    s += __shfl_xor(s, 1);
    s += __shfl_xor(s, 2);
    if ((t & 3) == 0)
        embh[b * DM_ + m] = s + b1h[m] + b1f[m];
}

// ---------------------------------------------------------------------------
// fp32 -> bf16 streaming convert (used for W1f and, in main path, feats)
// 8 elements per thread
// ---------------------------------------------------------------------------
__global__ __launch_bounds__(256) void k_cvt(
    const float* __restrict__ src, unsigned short* __restrict__ dst)
{
    size_t i = (size_t)blockIdx.x * 256 + threadIdx.x;
    float4 a = ((const float4*)src)[2 * i];
    float4 b = ((const float4*)src)[2 * i + 1];
    uint4 r;
    r.x = pack_rhu(a.x, a.y);
    r.y = pack_rhu(a.z, a.w);
    r.z = pack_rhu(b.x, b.y);
    r.w = pack_rhu(b.z, b.w);
    ((uint4*)dst)[i] = r;
}

// ---------------------------------------------------------------------------
// MAIN GEMM (bf16 A from pre-converted feats): m97 structure + 2-deep
// prefetch pipeline (T3+T4 minimal form):
//   128(M) x 128(N) x BK=32, mfma_f32_16x16x32_bf16, 4 waves as 2x2 (64x64).
//   LDS TRIPLE-buffered 3 x (8 KB A + 8 KB B) = 48 KB, chunk-of-8 layout
//   [c][row], 16B slots. ALL staging via global_load_lds width 16.
//   Pipeline: prologue issues tiles 0,1; per iter: vmcnt(4) (current tile
//   done, next still in flight) -> s_barrier -> issue tile kt+2 -> ds_read
//   -> MFMA. Buffer written at iter kt (tile kt+2) was last read at iter
//   kt-1, so the single barrier covers the WAR hazard.
//   Grid 1D 2048 swizzled: 4 bx-sharers of an A-tile are == mod 8 -> same XCD.
//   Epilogue: tanh(acc+embh)*w2, 16-lane reduce -> plog[bx*2+wn][B][S]
// ---------------------------------------------------------------------------
__global__ __launch_bounds__(256) void k_gemm_bf(
    const unsigned short* __restrict__ fb, const unsigned short* __restrict__ wb,
    const float* __restrict__ embh, const float* __restrict__ w2,
    float* __restrict__ plog)
{
    __shared__ bf16x8 As[3][4 * 128];   // 3 x 8 KB
    __shared__ bf16x8 Bs[3][4 * 128];   // 3 x 8 KB

    const int t    = threadIdx.x;
    const int lane = t & 63;
    const int w    = t >> 6;
    const int wm   = w >> 1;
    const int wn   = w & 1;
    const int quad = lane >> 4;
    const int l16  = lane & 15;

    const int blk   = blockIdx.x;
    const int panel = blk >> 5;
    const int sub   = blk & 31;
    const int bx    = sub >> 3;                // 0..3   N tile
    const int by    = panel * 8 + (sub & 7);   // 0..511 M tile

    // staging: wave w covers k-chunk c=w; 2 instrs cover rows 0..63 / 64..127
    const unsigned short* aG0 = fb + ((size_t)(by * 128) + lane) * DF_ + w * 8;
    const unsigned short* aG1 = aG0 + (size_t)64 * DF_;
    const unsigned short* bG0 = wb + ((size_t)(bx * 128) + lane) * DF_ + w * 8;
    const unsigned short* bG1 = bG0 + (size_t)64 * DF_;

    f32x4 acc[4][4];
    const f32x4 zero = {0.0f, 0.0f, 0.0f, 0.0f};
    #pragma unroll
    for (int i = 0; i < 4; ++i)
        #pragma unroll
        for (int j = 0; j < 4; ++j) acc[i][j] = zero;

    // issue one tile's staging (4 global_load_lds per wave -> vmcnt +4)
    auto stage = [&](int kt, int buf) {
        load_lds16(aG0 + kt * 32, &As[buf][w * 128]);
        load_lds16(aG1 + kt * 32, &As[buf][w * 128 + 64]);
        load_lds16(bG0 + kt * 32, &Bs[buf][w * 128]);
        load_lds16(bG1 + kt * 32, &Bs[buf][w * 128 + 64]);
    };

    stage(0, 0);
    stage(1, 1);

    int cur = 0;
    for (int kt = 0; kt < DF_ / 32; ++kt) {
        // tile kt's 4 loads done; tile kt+1's 4 may remain in flight
        if (kt < DF_ / 32 - 1)
            asm volatile("s_waitcnt vmcnt(4)" ::: "memory");
        else
            asm volatile("s_waitcnt vmcnt(0)" ::: "memory");
        __builtin_amdgcn_s_barrier();

        // prefetch tile kt+2 into the buffer last read at iter kt-1
        if (kt + 2 < DF_ / 32) {
            int nxt = (cur == 0) ? 2 : cur - 1;   // (cur+2)%3
            stage(kt + 2, nxt);
        }

        bf16x8 af[4], bfr[4];
        #pragma unroll
        for (int mi = 0; mi < 4; ++mi)
            af[mi] = As[cur][quad * 128 + wm * 64 + mi * 16 + l16];
        #pragma unroll
        for (int nj = 0; nj < 4; ++nj)
            bfr[nj] = Bs[cur][quad * 128 + wn * 64 + nj * 16 + l16];

        __builtin_amdgcn_s_setprio(1);
        #pragma unroll
        for (int mi = 0; mi < 4; ++mi)
            #pragma unroll
            for (int nj = 0; nj < 4; ++nj)
                acc[mi][nj] = __builtin_amdgcn_mfma_f32_16x16x32_bf16(
                    af[mi], bfr[nj], acc[mi][nj], 0, 0, 0);
        __builtin_amdgcn_s_setprio(0);

        cur = (cur == 2) ? 0 : cur + 1;
    }

    // epilogue (validated in R1): C/D 16x16 layout col=l16, row=quad*4+reg
    const int bIdx = by >> 4;
    float ew[4], wv[4];
    #pragma unroll
    for (int nj = 0; nj < 4; ++nj) {
        int c = bx * 128 + wn * 64 + nj * 16 + l16;
        ew[nj] = embh[bIdx * DM_ + c];
        wv[nj] = w2[c];
    }
    float* plw = plog + (size_t)(bx * 2 + wn) * MTOT + bIdx * S_;
    #pragma unroll
    for (int mi = 0; mi < 4; ++mi) {
        #pragma unroll
        for (int reg = 0; reg < 4; ++reg) {
            float p = 0.0f;
            #pragma unroll
            for (int nj = 0; nj < 4; ++nj)
                p += tanh_fast(acc[mi][nj][reg] + ew[nj]) * wv[nj];
            p += __shfl_xor(p, 1);
            p += __shfl_xor(p, 2);
            p += __shfl_xor(p, 4);
            p += __shfl_xor(p, 8);
            if (l16 == 0) {
                int rowl = wm * 64 + mi * 16 + quad * 4 + reg;
                int s = (by * 128 + rowl) & (S_ - 1);
                plw[s] = p;
            }
        }
    }
}

// ---------------------------------------------------------------------------
// FALLBACK GEMM (fp32 A, in-kernel cheap pack) — R1 structure, used only if
// ws is too small for the bf16 feats copy.
// ---------------------------------------------------------------------------
__global__ __launch_bounds__(256) void k_gemm_f32(
    const float* __restrict__ feats, const unsigned short* __restrict__ w1fb,
    const float* __restrict__ embh, const float* __restrict__ w2,
    float* __restrict__ plog)
{
    __shared__ bf16x8 As[4 * 128];
    __shared__ bf16x8 Bs[4 * 128];

    const int t    = threadIdx.x;
    const int lane = t & 63;
    const int w    = t >> 6;
    const int wm   = w >> 1;
    const int wn   = w & 1;
    const int quad = lane >> 4;
    const int l16  = lane & 15;
    const int blk   = blockIdx.x;
    const int panel = blk >> 5;
    const int sub   = blk & 31;
    const int bx    = sub >> 3;
    const int by    = panel * 8 + (sub & 7);

    const int sRow = t >> 1;
    const int sK   = (t & 1) * 16;
    const int c0   = sK >> 3;
    const float*          aG = feats + (size_t)(by * 128 + sRow) * DF_ + sK;
    const unsigned short* bG = w1fb  + (size_t)(bx * 128 + sRow) * DF_ + sK;

    f32x4 acc[4][4];
    const f32x4 zero = {0.0f, 0.0f, 0.0f, 0.0f};
    #pragma unroll
    for (int i = 0; i < 4; ++i)
        #pragma unroll
        for (int j = 0; j < 4; ++j) acc[i][j] = zero;

    for (int kt = 0; kt < DF_ / 32; ++kt) {
        float4 a0 = *(const float4*)(aG + kt * 32);
        float4 a1 = *(const float4*)(aG + kt * 32 + 4);
        float4 a2 = *(const float4*)(aG + kt * 32 + 8);
        float4 a3 = *(const float4*)(aG + kt * 32 + 12);
        uint4  b0 = *(const uint4*)(bG + kt * 32);
        uint4  b1 = *(const uint4*)(bG + kt * 32 + 8);

        __syncthreads();

        union { unsigned u[4]; bf16x8 v; } pa;
        pa.u[0] = pack_rhu(a0.x, a0.y);
        pa.u[1] = pack_rhu(a0.z, a0.w);
        pa.u[2] = pack_rhu(a1.x, a1.y);
        pa.u[3] = pack_rhu(a1.z, a1.w);
        As[c0 * 128 + sRow] = pa.v;
        pa.u[0] = pack_rhu(a2.x, a2.y);
        pa.u[1] = pack_rhu(a2.z, a2.w);
        pa.u[2] = pack_rhu(a3.x, a3.y);
        pa.u[3] = pack_rhu(a3.z, a3.w);
        As[(c0 + 1) * 128 + sRow] = pa.v;

        union { uint4 q; bf16x8 v; } pb;
        pb.q = b0;
        Bs[c0 * 128 + sRow] = pb.v;
        pb.q = b1;
        Bs[(c0 + 1) * 128 + sRow] = pb.v;

        __syncthreads();

        bf16x8 af[4], bfr[4];
        #pragma unroll
        for (int mi = 0; mi < 4; ++mi)
            af[mi] = As[quad * 128 + wm * 64 + mi * 16 + l16];
        #pragma unroll
        for (int nj = 0; nj < 4; ++nj)
            bfr[nj] = Bs[quad * 128 + wn * 64 + nj * 16 + l16];

        #pragma unroll
        for (int mi = 0; mi < 4; ++mi)
            #pragma unroll
            for (int nj = 0; nj < 4; ++nj)
                acc[mi][nj] = __builtin_amdgcn_mfma_f32_16x16x32_bf16(
                    af[mi], bfr[nj], acc[mi][nj], 0, 0, 0);
    }

    const int bIdx = by >> 4;
    float ew[4], wv[4];
    #pragma unroll
    for (int nj = 0; nj < 4; ++nj) {
        int c = bx * 128 + wn * 64 + nj * 16 + l16;
        ew[nj] = embh[bIdx * DM_ + c];
        wv[nj] = w2[c];
    }
    float* plw = plog + (size_t)(bx * 2 + wn) * MTOT + bIdx * S_;
    #pragma unroll
    for (int mi = 0; mi < 4; ++mi) {
        #pragma unroll
        for (int reg = 0; reg < 4; ++reg) {
            float p = 0.0f;
            #pragma unroll
            for (int nj = 0; nj < 4; ++nj)
                p += tanh_fast(acc[mi][nj][reg] + ew[nj]) * wv[nj];
            p += __shfl_xor(p, 1);
            p += __shfl_xor(p, 2);
            p += __shfl_xor(p, 4);
            p += __shfl_xor(p, 8);
            if (l16 == 0) {
                int rowl = wm * 64 + mi * 16 + quad * 4 + reg;
                int s = (by * 128 + rowl) & (S_ - 1);
                plw[s] = p;
            }
        }
    }
}

// ---------------------------------------------------------------------------
// combine 8 partials, softmax over S per batch row
// ---------------------------------------------------------------------------
__global__ __launch_bounds__(256) void k_softmax(
    const float* __restrict__ plog, float* __restrict__ probs_out)
{
    int b = blockIdx.x;
    int t = threadIdx.x;
    float l[8];
    #pragma unroll
    for (int i = 0; i < 8; ++i) {
        int s = t + i * 256;
        float sum = 0.0f;
        #pragma unroll
        for (int p = 0; p < 8; ++p)
            sum += plog[(size_t)p * MTOT + b * S_ + s];
        l[i] = sum;
    }
    float mx = l[0];
    #pragma unroll
    for (int i = 1; i < 8; ++i) mx = fmaxf(mx, l[i]);
    #pragma unroll
    for (int off = 1; off < 64; off <<= 1) mx = fmaxf(mx, __shfl_xor(mx, off));
    __shared__ float redm[4];
    __shared__ float reds[4];
    int wid = t >> 6;
    if ((t & 63) == 0) redm[wid] = mx;
    __syncthreads();
    mx = fmaxf(fmaxf(redm[0], redm[1]), fmaxf(redm[2], redm[3]));

    float e[8];
    float es = 0.0f;
    #pragma unroll
    for (int i = 0; i < 8; ++i) {
        e[i] = __expf(l[i] - mx);
        es += e[i];
    }
    #pragma unroll
    for (int off = 1; off < 64; off <<= 1) es += __shfl_xor(es, off);
    if ((t & 63) == 0) reds[wid] = es;
    __syncthreads();
    es = reds[0] + reds[1] + reds[2] + reds[3];
    float inv = 1.0f / es;
    #pragma unroll
    for (int i = 0; i < 8; ++i)
        probs_out[b * S_ + t + i * 256] = e[i] * inv;
}

// ---------------------------------------------------------------------------
// context partials (bf16 feats), 16B loads per lane.
//   grid (B_, 16), 256 threads. Thread (half = t>>7, dt = t&127) owns
//   d = dt*8..dt*8+7 and s-range z*128 + half*64 .. +63.
//   ctxp[(z*2+half)][b][d] = sum_{s in range} probs[b][s] * feats[b][s][d]
//   -> 32 partials, 4 MB in ws
// ---------------------------------------------------------------------------
__global__ __launch_bounds__(256) void k_context_bf(
    const unsigned short* __restrict__ fb, const float* __restrict__ probs,
    float* __restrict__ ctxp)
{
    int t    = threadIdx.x;
    int b    = blockIdx.x;
    int z    = blockIdx.y;        // 0..15
    int half = t >> 7;            // 0,1
    int dt   = t & 127;           // d/8
    int s0   = z * 128 + half * 64;

    const uint4* f  = (const uint4*)(fb + (size_t)(b * S_ + s0) * DF_) + dt;
    const float* pr = probs + b * S_ + s0;

    float acc[8];
    #pragma unroll
    for (int j = 0; j < 8; ++j) acc[j] = 0.0f;

    #pragma unroll 8
    for (int i = 0; i < 64; ++i) {
        uint4 v = f[(size_t)i * (DF_ / 8)];
        float p = pr[i];
        acc[0] += p * bflo(v.x);
        acc[1] += p * bfhi(v.x);
        acc[2] += p * bflo(v.y);
        acc[3] += p * bfhi(v.y);
        acc[4] += p * bflo(v.z);
        acc[5] += p * bfhi(v.z);
        acc[6] += p * bflo(v.w);
        acc[7] += p * bfhi(v.w);
    }

    float4* o = (float4*)(ctxp + ((size_t)(z * 2 + half) * B_ + b) * DF_ + dt * 8);
    o[0] = make_float4(acc[0], acc[1], acc[2], acc[3]);
    o[1] = make_float4(acc[4], acc[5], acc[6], acc[7]);
}

// fp32-feats fallback context (32 partials of 64 rows each)
__global__ __launch_bounds__(256) void k_context_f32(
    const float* __restrict__ feats, const float* __restrict__ probs,
    float* __restrict__ ctxp)
{
    int d  = blockIdx.x * 256 + threadIdx.x;
    int b  = blockIdx.y;
    int z  = blockIdx.z;          // 0..31
    const float* f  = feats + ((size_t)b * S_ + z * 64) * DF_ + d;
    const float* pr = probs + b * S_ + z * 64;
    float acc = 0.0f;
    #pragma unroll 4
    for (int i = 0; i < 64; ++i)
        acc += pr[i] * f[(size_t)i * DF_];
    ctxp[((size_t)z * B_ + b) * DF_ + d] = acc;
}

__global__ __launch_bounds__(256) void k_ctx_red(
    const float* __restrict__ ctxp, float* __restrict__ ctx)
{
    int i = blockIdx.x * 256 + threadIdx.x;
    float s = 0.0f;
    #pragma unroll
    for (int z = 0; z < 32; ++z)
        s += ctxp[(size_t)z * B_ * DF_ + i];
    ctx[i] = s;
}

// ---------------------------------------------------------------------------
extern "C" void kernel_launch(void* const* d_in, const int* in_sizes, int n_in,
                              void* d_out, int out_size, void* d_ws, size_t ws_size,
                              hipStream_t stream)
{
    const float* hidden = (const float*)d_in[0];
    const float* feats  = (const float*)d_in[1];
    const float* W1h    = (const float*)d_in[2];
    const float* b1h    = (const float*)d_in[3];
    const float* W1f    = (const float*)d_in[4];
    const float* b1f    = (const float*)d_in[5];
    const float* w2     = (const float*)d_in[6];

    float* out   = (float*)d_out;
    float* ctx   = out;              // [B, DF]   (output 0)
    float* probs = out + B_ * DF_;   // [B, 1, S] (output 1)

    char* ws = (char*)d_ws;
    float*          embh  = (float*)ws;                              // 64 KB
    unsigned short* w1fb  = (unsigned short*)(ws + (64 << 10));      // 1 MB
    float*          plog  = (float*)(ws + (64 << 10) + (1 << 20));   // 2 MB
    float*          ctxp  = (float*)(ws + (64 << 10) + (3 << 20));   // 4 MB
    unsigned short* featb = (unsigned short*)(ws + (8 << 20));       // 128 MB

    const bool big_ws = ws_size >= ((size_t)8 << 20) + ((size_t)B_ * S_ * DF_ * 2);

    k_embh<<<dim3(B_, DM_ / 64), 256, 0, stream>>>(hidden, W1h, b1h, b1f, embh);
    k_cvt<<<dim3((DM_ * DF_ / 8) / 256), 256, 0, stream>>>(W1f, w1fb);

    if (big_ws) {
        k_cvt<<<dim3(((size_t)MTOT * DF_ / 8) / 256), 256, 0, stream>>>(feats, featb);
        k_gemm_bf<<<dim3((MTOT / 128) * (DM_ / 128)), 256, 0, stream>>>(
            featb, w1fb, embh, w2, plog);
        k_softmax<<<dim3(B_), 256, 0, stream>>>(plog, probs);
        k_context_bf<<<dim3(B_, 16), 256, 0, stream>>>(featb, probs, ctxp);
    } else {
        k_gemm_f32<<<dim3((MTOT / 128) * (DM_ / 128)), 256, 0, stream>>>(
            feats, w1fb, embh, w2, plog);
        k_softmax<<<dim3(B_), 256, 0, stream>>>(plog, probs);
        k_context_f32<<<dim3(DF_ / 256, B_, 32), 256, 0, stream>>>(feats, probs, ctxp);
    }
    k_ctx_red<<<dim3(B_ * DF_ / 256), 256, 0, stream>>>(ctxp, ctx);
}

// Round 2
// 520.080 us; speedup vs baseline: 1.1139x; 1.1139x over previous
//
#include <hip/hip_runtime.h>
#include <hip/hip_bf16.h>
#include <cstdint>
#include <cstddef>

#define B_   32
#define S_   2048
#define DH_  1024
#define DF_  1024
#define DM_  512
#define MTOT (B_ * S_)   // 65536
#define NT_  (DF_ / 32)  // 32 K-tiles of BK=32

typedef __attribute__((ext_vector_type(8))) short bf16x8;
typedef __attribute__((ext_vector_type(4))) float f32x4;

#define AS1 __attribute__((address_space(1)))
#define AS3 __attribute__((address_space(3)))

static __device__ __forceinline__ void load_lds16(const void* g, void* l) {
    __builtin_amdgcn_global_load_lds((const AS1 unsigned*)g, (AS3 unsigned*)l,
                                     16, 0, 0);
}

// fp32 pair -> packed bf16, round-half-up (cheap)
static __device__ __forceinline__ unsigned pack_rhu(float a, float b) {
    unsigned ua = (__float_as_uint(a) + 0x8000u) >> 16;
    unsigned ub = (__float_as_uint(b) + 0x8000u) & 0xFFFF0000u;
    return ua | ub;
}

static __device__ __forceinline__ float tanh_fast(float x) {
    float e = __expf(2.0f * x);
    return 1.0f - 2.0f / (e + 1.0f);
}

static __device__ __forceinline__ float bflo(unsigned v) {
    return __uint_as_float(v << 16);
}
static __device__ __forceinline__ float bfhi(unsigned v) {
    return __uint_as_float(v & 0xFFFF0000u);
}

// ---------------------------------------------------------------------------
// embh[b][m] = dot(hidden[b], W1h[m]) + b1h[m] + b1f[m]
// ---------------------------------------------------------------------------
__global__ __launch_bounds__(256) void k_embh(
    const float* __restrict__ hidden, const float* __restrict__ W1h,
    const float* __restrict__ b1h, const float* __restrict__ b1f,
    float* __restrict__ embh)
{
    int b  = blockIdx.x;
    int mg = blockIdx.y;
    int t  = threadIdx.x;
    int m  = mg * 64 + (t >> 2);
    int kp = (t & 3) * 256;
    const float4* h4 = (const float4*)(hidden + (size_t)b * DH_ + kp);
    const float4* w4 = (const float4*)(W1h + (size_t)m * DH_ + kp);
    float s = 0.0f;
    #pragma unroll 8
    for (int i = 0; i < 64; ++i) {
        float4 a = h4[i];
        float4 w = w4[i];
        s += a.x * w.x + a.y * w.y + a.z * w.z + a.w * w.w;
    }
    s += __shfl_xor(s, 1);
    s += __shfl_xor(s, 2);
    if ((t & 3) == 0)
        embh[b * DM_ + m] = s + b1h[m] + b1f[m];
}

// ---------------------------------------------------------------------------
// fp32 -> bf16 streaming convert, grid-stride, 1 float4 (16B) per thread/iter
// (perfectly coalesced: lane i reads [16i,16i+16), writes 8B)
// ---------------------------------------------------------------------------
__global__ __launch_bounds__(256) void k_cvt(
    const float* __restrict__ src, unsigned short* __restrict__ dst, long n4)
{
    long stride = (long)gridDim.x * 256;
    for (long i = (long)blockIdx.x * 256 + threadIdx.x; i < n4; i += stride) {
        float4 a = ((const float4*)src)[i];
        uint2 r;
        r.x = pack_rhu(a.x, a.y);
        r.y = pack_rhu(a.z, a.w);
        ((uint2*)dst)[i] = r;
    }
}

// ---------------------------------------------------------------------------
// MAIN GEMM — 256x256 tile, 8 waves (2M x 4N), BK=32, 16x16x32 bf16 MFMA.
// Phase-split schedule (T3+T4+T2+T5 re-derived for this shape):
//   * 4 LDS buffers (A,B each [256][32] bf16 = 16KB; total 128KB), depth-3
//     prefetch, steady-state s_waitcnt vmcnt(8) — queue never drains.
//   * 2 phases/K-tile: {ds_read subtile; 2x global_load_lds; s_barrier;
//     lgkmcnt(0)+sched_barrier; setprio(1) 16xMFMA setprio(0); s_barrier}.
//   * LDS swizzle: 16B slot ^= (row>>1)&3 (64B rows) — applied on BOTH the
//     staging global source (pre-swizzle, lane-pure: (lane&3)^((lane>>3)&3))
//     and the ds_read slot (quad ^ ((l16>>1)&3)); 2-way residual = free.
//   * Grid 512 = 256 M-tiles x 2 N-tiles, swizzled so the (by, bx=0/1) pair
//     lands on one XCD.
// Epilogue: tanh(acc+embh)*w2, 16-lane shfl reduce -> plog[bx*4+wn][B][S].
// ---------------------------------------------------------------------------
__global__ __launch_bounds__(512, 2) void k_gemm_bf(
    const unsigned short* __restrict__ fb, const unsigned short* __restrict__ wb,
    const float* __restrict__ embh, const float* __restrict__ w2,
    float* __restrict__ plog)
{
    __shared__ bf16x8 As[4][1024];   // 4 x 16 KB
    __shared__ bf16x8 Bs[4][1024];   // 4 x 16 KB

    const int t    = threadIdx.x;
    const int lane = t & 63;
    const int w    = t >> 6;        // 0..7
    const int wm   = w >> 2;        // 0..1 : 128-row group
    const int wn   = w & 3;         // 0..3 : 64-col group
    const int quad = lane >> 4;
    const int l16  = lane & 15;

    // XCD swizzle: pair (by,bx=0/1) -> same XCD slot (g mod 8)
    const int g    = blockIdx.x;               // 0..511
    const int flat = (g & 7) * 64 + (g >> 3);
    const int by   = flat >> 1;                // 0..255
    const int bx   = flat & 1;                 // 0..1

    // staging source (pre-swizzled chunk; lane-pure since base rows are %8==0)
    const int swz = ((lane & 3) ^ ((lane >> 3) & 3)) * 8;
    const unsigned short* srcA =
        fb + ((size_t)(by * 256 + w * 32 + (lane >> 2))) * DF_ + swz;
    const unsigned short* srcB =
        wb + ((size_t)(bx * 256 + w * 32 + (lane >> 2))) * DF_ + swz;

    f32x4 acc[8][4];
    const f32x4 zero = {0.0f, 0.0f, 0.0f, 0.0f};
    #pragma unroll
    for (int i = 0; i < 8; ++i)
        #pragma unroll
        for (int j = 0; j < 4; ++j) acc[i][j] = zero;

    // one K-tile of A (or B) staging: 2 x global_load_lds per wave
    auto stageA = [&](int kt) {
        load_lds16(srcA + kt * 32,            &As[kt & 3][(w * 2) * 64]);
        load_lds16(srcA + 16 * DF_ + kt * 32, &As[kt & 3][(w * 2 + 1) * 64]);
    };
    auto stageB = [&](int kt) {
        load_lds16(srcB + kt * 32,            &Bs[kt & 3][(w * 2) * 64]);
        load_lds16(srcB + 16 * DF_ + kt * 32, &Bs[kt & 3][(w * 2 + 1) * 64]);
    };

    // prologue: tiles 0,1,2 in flight (12 loads; order [A,A,B,B] per tile)
    stageA(0); stageB(0);
    stageA(1); stageB(1);
    stageA(2); stageB(2);

    const int sw4 = quad ^ ((l16 >> 1) & 3);
    const int sa  = (wm * 128 + l16) * 4 + sw4;
    const int sb  = (wn * 64 + l16) * 4 + sw4;

    for (int kt = 0; kt < NT_; ++kt) {
        const int buf = kt & 3;
        // retire THIS tile's 4 loads; keep kt+1/kt+2 (8) in flight
        if (kt < NT_ - 2)       asm volatile("s_waitcnt vmcnt(8)" ::: "memory");
        else if (kt == NT_ - 2) asm volatile("s_waitcnt vmcnt(4)" ::: "memory");
        else                    asm volatile("s_waitcnt vmcnt(0)" ::: "memory");
        __builtin_amdgcn_s_barrier();

        bf16x8 af[4], bfr[4];
        // ---- phase 0: mi 0..3 ----
        #pragma unroll
        for (int nj = 0; nj < 4; ++nj) bfr[nj] = Bs[buf][sb + nj * 64];
        #pragma unroll
        for (int mi = 0; mi < 4; ++mi) af[mi] = As[buf][sa + mi * 64];
        if (kt < NT_ - 3) stageA(kt + 3);
        __builtin_amdgcn_s_barrier();
        asm volatile("s_waitcnt lgkmcnt(0)" ::: "memory");
        __builtin_amdgcn_sched_barrier(0);
        __builtin_amdgcn_s_setprio(1);
        #pragma unroll
        for (int mi = 0; mi < 4; ++mi)
            #pragma unroll
            for (int nj = 0; nj < 4; ++nj)
                acc[mi][nj] = __builtin_amdgcn_mfma_f32_16x16x32_bf16(
                    af[mi], bfr[nj], acc[mi][nj], 0, 0, 0);
        __builtin_amdgcn_s_setprio(0);
        __builtin_amdgcn_s_barrier();

        // ---- phase 1: mi 4..7 ----
        #pragma unroll
        for (int mi = 0; mi < 4; ++mi) af[mi] = As[buf][sa + 256 + mi * 64];
        if (kt < NT_ - 3) stageB(kt + 3);
        __builtin_amdgcn_s_barrier();
        asm volatile("s_waitcnt lgkmcnt(0)" ::: "memory");
        __builtin_amdgcn_sched_barrier(0);
        __builtin_amdgcn_s_setprio(1);
        #pragma unroll
        for (int mi = 0; mi < 4; ++mi)
            #pragma unroll
            for (int nj = 0; nj < 4; ++nj)
                acc[4 + mi][nj] = __builtin_amdgcn_mfma_f32_16x16x32_bf16(
                    af[mi], bfr[nj], acc[4 + mi][nj], 0, 0, 0);
        __builtin_amdgcn_s_setprio(0);
        // phase-1 close barrier = next tile's post-vmcnt barrier
    }

    // epilogue: C/D layout col=l16 (b-side), row=quad*4+reg (a-side) — proven
    const int bIdx = by >> 3;
    float ew[4], wv[4];
    #pragma unroll
    for (int nj = 0; nj < 4; ++nj) {
        int c = bx * 256 + wn * 64 + nj * 16 + l16;
        ew[nj] = embh[bIdx * DM_ + c];
        wv[nj] = w2[c];
    }
    float* plw = plog + (size_t)(bx * 4 + wn) * MTOT + bIdx * S_;
    const int rbase = (by * 256 + wm * 128) & (S_ - 1);
    #pragma unroll
    for (int mi = 0; mi < 8; ++mi) {
        #pragma unroll
        for (int reg = 0; reg < 4; ++reg) {
            float p = 0.0f;
            #pragma unroll
            for (int nj = 0; nj < 4; ++nj)
                p += tanh_fast(acc[mi][nj][reg] + ew[nj]) * wv[nj];
            p += __shfl_xor(p, 1);
            p += __shfl_xor(p, 2);
            p += __shfl_xor(p, 4);
            p += __shfl_xor(p, 8);
            if (l16 == 0)
                plw[rbase + mi * 16 + quad * 4 + reg] = p;
        }
    }
}

// ---------------------------------------------------------------------------
// FALLBACK GEMM (fp32 A, in-kernel cheap pack) — used only if ws too small.
// ---------------------------------------------------------------------------
__global__ __launch_bounds__(256) void k_gemm_f32(
    const float* __restrict__ feats, const unsigned short* __restrict__ w1fb,
    const float* __restrict__ embh, const float* __restrict__ w2,
    float* __restrict__ plog)
{
    __shared__ bf16x8 As[4 * 128];
    __shared__ bf16x8 Bs[4 * 128];

    const int t    = threadIdx.x;
    const int lane = t & 63;
    const int w    = t >> 6;
    const int wm   = w >> 1;
    const int wn   = w & 1;
    const int quad = lane >> 4;
    const int l16  = lane & 15;
    const int blk   = blockIdx.x;
    const int panel = blk >> 5;
    const int sub   = blk & 31;
    const int bx    = sub >> 3;
    const int by    = panel * 8 + (sub & 7);

    const int sRow = t >> 1;
    const int sK   = (t & 1) * 16;
    const int c0   = sK >> 3;
    const float*          aG = feats + (size_t)(by * 128 + sRow) * DF_ + sK;
    const unsigned short* bG = w1fb  + (size_t)(bx * 128 + sRow) * DF_ + sK;

    f32x4 acc[4][4];
    const f32x4 zero = {0.0f, 0.0f, 0.0f, 0.0f};
    #pragma unroll
    for (int i = 0; i < 4; ++i)
        #pragma unroll
        for (int j = 0; j < 4; ++j) acc[i][j] = zero;

    for (int kt = 0; kt < DF_ / 32; ++kt) {
        float4 a0 = *(const float4*)(aG + kt * 32);
        float4 a1 = *(const float4*)(aG + kt * 32 + 4);
        float4 a2 = *(const float4*)(aG + kt * 32 + 8);
        float4 a3 = *(const float4*)(aG + kt * 32 + 12);
        uint4  b0 = *(const uint4*)(bG + kt * 32);
        uint4  b1 = *(const uint4*)(bG + kt * 32 + 8);

        __syncthreads();

        union { unsigned u[4]; bf16x8 v; } pa;
        pa.u[0] = pack_rhu(a0.x, a0.y);
        pa.u[1] = pack_rhu(a0.z, a0.w);
        pa.u[2] = pack_rhu(a1.x, a1.y);
        pa.u[3] = pack_rhu(a1.z, a1.w);
        As[c0 * 128 + sRow] = pa.v;
        pa.u[0] = pack_rhu(a2.x, a2.y);
        pa.u[1] = pack_rhu(a2.z, a2.w);
        pa.u[2] = pack_rhu(a3.x, a3.y);
        pa.u[3] = pack_rhu(a3.z, a3.w);
        As[(c0 + 1) * 128 + sRow] = pa.v;

        union { uint4 q; bf16x8 v; } pb;
        pb.q = b0;
        Bs[c0 * 128 + sRow] = pb.v;
        pb.q = b1;
        Bs[(c0 + 1) * 128 + sRow] = pb.v;

        __syncthreads();

        bf16x8 af[4], bfr[4];
        #pragma unroll
        for (int mi = 0; mi < 4; ++mi)
            af[mi] = As[quad * 128 + wm * 64 + mi * 16 + l16];
        #pragma unroll
        for (int nj = 0; nj < 4; ++nj)
            bfr[nj] = Bs[quad * 128 + wn * 64 + nj * 16 + l16];

        #pragma unroll
        for (int mi = 0; mi < 4; ++mi)
            #pragma unroll
            for (int nj = 0; nj < 4; ++nj)
                acc[mi][nj] = __builtin_amdgcn_mfma_f32_16x16x32_bf16(
                    af[mi], bfr[nj], acc[mi][nj], 0, 0, 0);
    }

    const int bIdx = by >> 4;
    float ew[4], wv[4];
    #pragma unroll
    for (int nj = 0; nj < 4; ++nj) {
        int c = bx * 128 + wn * 64 + nj * 16 + l16;
        ew[nj] = embh[bIdx * DM_ + c];
        wv[nj] = w2[c];
    }
    float* plw = plog + (size_t)(bx * 2 + wn) * MTOT + bIdx * S_;
    #pragma unroll
    for (int mi = 0; mi < 4; ++mi) {
        #pragma unroll
        for (int reg = 0; reg < 4; ++reg) {
            float p = 0.0f;
            #pragma unroll
            for (int nj = 0; nj < 4; ++nj)
                p += tanh_fast(acc[mi][nj][reg] + ew[nj]) * wv[nj];
            p += __shfl_xor(p, 1);
            p += __shfl_xor(p, 2);
            p += __shfl_xor(p, 4);
            p += __shfl_xor(p, 8);
            if (l16 == 0) {
                int rowl = wm * 64 + mi * 16 + quad * 4 + reg;
                int s = (by * 128 + rowl) & (S_ - 1);
                plw[s] = p;
            }
        }
    }
}

// ---------------------------------------------------------------------------
// combine 8 partials, softmax over S per batch row
// ---------------------------------------------------------------------------
__global__ __launch_bounds__(256) void k_softmax(
    const float* __restrict__ plog, float* __restrict__ probs_out)
{
    int b = blockIdx.x;
    int t = threadIdx.x;
    float l[8];
    #pragma unroll
    for (int i = 0; i < 8; ++i) {
        int s = t + i * 256;
        float sum = 0.0f;
        #pragma unroll
        for (int p = 0; p < 8; ++p)
            sum += plog[(size_t)p * MTOT + b * S_ + s];
        l[i] = sum;
    }
    float mx = l[0];
    #pragma unroll
    for (int i = 1; i < 8; ++i) mx = fmaxf(mx, l[i]);
    #pragma unroll
    for (int off = 1; off < 64; off <<= 1) mx = fmaxf(mx, __shfl_xor(mx, off));
    __shared__ float redm[4];
    __shared__ float reds[4];
    int wid = t >> 6;
    if ((t & 63) == 0) redm[wid] = mx;
    __syncthreads();
    mx = fmaxf(fmaxf(redm[0], redm[1]), fmaxf(redm[2], redm[3]));

    float e[8];
    float es = 0.0f;
    #pragma unroll
    for (int i = 0; i < 8; ++i) {
        e[i] = __expf(l[i] - mx);
        es += e[i];
    }
    #pragma unroll
    for (int off = 1; off < 64; off <<= 1) es += __shfl_xor(es, off);
    if ((t & 63) == 0) reds[wid] = es;
    __syncthreads();
    es = reds[0] + reds[1] + reds[2] + reds[3];
    float inv = 1.0f / es;
    #pragma unroll
    for (int i = 0; i < 8; ++i)
        probs_out[b * S_ + t + i * 256] = e[i] * inv;
}

// ---------------------------------------------------------------------------
// context partials (bf16 feats), 16B loads per lane.
//   grid (B_, 16), 256 threads. Thread (half = t>>7, dt = t&127) owns
//   d = dt*8..dt*8+7 and s-range z*128 + half*64 .. +63.
//   ctxp[(z*2+half)][b][d] -> 32 partials, 4 MB in ws
// ---------------------------------------------------------------------------
__global__ __launch_bounds__(256) void k_context_bf(
    const unsigned short* __restrict__ fb, const float* __restrict__ probs,
    float* __restrict__ ctxp)
{
    int t    = threadIdx.x;
    int b    = blockIdx.x;
    int z    = blockIdx.y;        // 0..15
    int half = t >> 7;            // 0,1
    int dt   = t & 127;           // d/8
    int s0   = z * 128 + half * 64;

    const uint4* f  = (const uint4*)(fb + (size_t)(b * S_ + s0) * DF_) + dt;
    const float* pr = probs + b * S_ + s0;

    float acc[8];
    #pragma unroll
    for (int j = 0; j < 8; ++j) acc[j] = 0.0f;

    #pragma unroll 8
    for (int i = 0; i < 64; ++i) {
        uint4 v = f[(size_t)i * (DF_ / 8)];
        float p = pr[i];
        acc[0] += p * bflo(v.x);
        acc[1] += p * bfhi(v.x);
        acc[2] += p * bflo(v.y);
        acc[3] += p * bfhi(v.y);
        acc[4] += p * bflo(v.z);
        acc[5] += p * bfhi(v.z);
        acc[6] += p * bflo(v.w);
        acc[7] += p * bfhi(v.w);
    }

    float4* o = (float4*)(ctxp + ((size_t)(z * 2 + half) * B_ + b) * DF_ + dt * 8);
    o[0] = make_float4(acc[0], acc[1], acc[2], acc[3]);
    o[1] = make_float4(acc[4], acc[5], acc[6], acc[7]);
}

// fp32-feats fallback context (32 partials of 64 rows each)
__global__ __launch_bounds__(256) void k_context_f32(
    const float* __restrict__ feats, const float* __restrict__ probs,
    float* __restrict__ ctxp)
{
    int d  = blockIdx.x * 256 + threadIdx.x;
    int b  = blockIdx.y;
    int z  = blockIdx.z;          // 0..31
    const float* f  = feats + ((size_t)b * S_ + z * 64) * DF_ + d;
    const float* pr = probs + b * S_ + z * 64;
    float acc = 0.0f;
    #pragma unroll 4
    for (int i = 0; i < 64; ++i)
        acc += pr[i] * f[(size_t)i * DF_];
    ctxp[((size_t)z * B_ + b) * DF_ + d] = acc;
}

__global__ __launch_bounds__(256) void k_ctx_red(
    const float* __restrict__ ctxp, float* __restrict__ ctx)
{
    int i = blockIdx.x * 256 + threadIdx.x;
    float s = 0.0f;
    #pragma unroll
    for (int z = 0; z < 32; ++z)
        s += ctxp[(size_t)z * B_ * DF_ + i];
    ctx[i] = s;
}

// ---------------------------------------------------------------------------
extern "C" void kernel_launch(void* const* d_in, const int* in_sizes, int n_in,
                              void* d_out, int out_size, void* d_ws, size_t ws_size,
                              hipStream_t stream)
{
    const float* hidden = (const float*)d_in[0];
    const float* feats  = (const float*)d_in[1];
    const float* W1h    = (const float*)d_in[2];
    const float* b1h    = (const float*)d_in[3];
    const float* W1f    = (const float*)d_in[4];
    const float* b1f    = (const float*)d_in[5];
    const float* w2     = (const float*)d_in[6];

    float* out   = (float*)d_out;
    float* ctx   = out;              // [B, DF]   (output 0)
    float* probs = out + B_ * DF_;   // [B, 1, S] (output 1)

    char* ws = (char*)d_ws;
    float*          embh  = (float*)ws;                              // 64 KB
    unsigned short* w1fb  = (unsigned short*)(ws + (64 << 10));      // 1 MB
    float*          plog  = (float*)(ws + (64 << 10) + (1 << 20));   // 2 MB
    float*          ctxp  = (float*)(ws + (64 << 10) + (3 << 20));   // 4 MB
    unsigned short* featb = (unsigned short*)(ws + (8 << 20));       // 128 MB

    const bool big_ws = ws_size >= ((size_t)8 << 20) + ((size_t)B_ * S_ * DF_ * 2);

    k_embh<<<dim3(B_, DM_ / 64), 256, 0, stream>>>(hidden, W1h, b1h, b1f, embh);
    k_cvt<<<dim3(512), 256, 0, stream>>>(W1f, w1fb, (long)DM_ * DF_ / 4);

    if (big_ws) {
        k_cvt<<<dim3(8192), 256, 0, stream>>>(feats, featb, (long)MTOT * DF_ / 4);
        k_gemm_bf<<<dim3((MTOT / 256) * (DM_ / 256)), 512, 0, stream>>>(
            featb, w1fb, embh, w2, plog);
        k_softmax<<<dim3(B_), 256, 0, stream>>>(plog, probs);
        k_context_bf<<<dim3(B_, 16), 256, 0, stream>>>(featb, probs, ctxp);
    } else {
        k_gemm_f32<<<dim3((MTOT / 128) * (DM_ / 128)), 256, 0, stream>>>(
            feats, w1fb, embh, w2, plog);
        k_softmax<<<dim3(B_), 256, 0, stream>>>(plog, probs);
        k_context_f32<<<dim3(DF_ / 256, B_, 32), 256, 0, stream>>>(feats, probs, ctxp);
    }
    k_ctx_red<<<dim3(B_ * DF_ / 256), 256, 0, stream>>>(ctxp, ctx);
}